// Round 8
// baseline (172.979 us; speedup 1.0000x reference)
//
#include <hip/hip_runtime.h>
#include <cstdint>
#include <cstddef>

#define B 4096
#define D 128
#define MARGIN_F 0.2f
#define CW 256            // per-row candidate capacity

typedef short bf16x8 __attribute__((ext_vector_type(8)));
typedef float f32x4 __attribute__((ext_vector_type(4)));
typedef uint32_t u32x4 __attribute__((ext_vector_type(4)));

// order-preserving float->uint (ascending uint == ascending float)
__device__ __forceinline__ uint32_t xform_key(float f) {
    uint32_t u = __float_as_uint(f);
    return u ^ (uint32_t)((((int32_t)u) >> 31) | 0x80000000);
}
// decode 16-bit truncated key (bucket center under round-to-nearest encode)
__device__ __forceinline__ float unxform16(uint32_t k16) {
    uint32_t u = k16 << 16;
    u = (u & 0x80000000u) ? (u ^ 0x80000000u) : ~u;
    return __uint_as_float(u);
}
__device__ __forceinline__ unsigned short f2bf(float f) {   // round-nearest-even
    uint32_t u = __float_as_uint(f);
    return (unsigned short)((u + 0x7FFFu + ((u >> 16) & 1u)) >> 16);
}

// fused: zero out, sq[i] = ||R[i]||^2, R -> Rb (bf16 rne)
__global__ __launch_bounds__(256) void prep_kernel(const float* __restrict__ R,
                                                   float* __restrict__ sq,
                                                   unsigned short* __restrict__ Rb,
                                                   float* __restrict__ out) {
    if (blockIdx.x == 0 && threadIdx.x == 0) out[0] = 0.0f;
    int wave = threadIdx.x >> 6;
    int lane = threadIdx.x & 63;
    int row  = blockIdx.x * 4 + wave;
    const float2* R2 = (const float2*)R + (size_t)row * (D / 2);
    float2 v = R2[lane];
    ushort2 o; o.x = f2bf(v.x); o.y = f2bf(v.y);
    *(ushort2*)(Rb + (size_t)row * D + lane * 2) = o;
    float s = v.x * v.x + v.y * v.y;
#pragma unroll
    for (int off = 32; off > 0; off >>= 1) s += __shfl_down(s, off);
    if (lane == 0) sq[row] = s;
}

// R8 SPLIT, kernel A: MFMA gram + dist/margin -> 16-bit keys in GLOBAL K.
// 256 blocks x 512t, 16 rows/block. 80KB LDS pad clamps the compile-time
// occupancy target at 2 blocks/CU -> VGPR budget 128 -> no allocator crunch
// (R1/R2/R6/R7 lesson: any reachable higher-occupancy step triggers a VGPR
// crunch that wrecks codegen; LDS-binding is the only reliable way to stop
// it -- the R4/R5 mechanism). Next-tile prefetch hides L2 latency.
__global__ __launch_bounds__(512) void gram_keys(const unsigned short* __restrict__ Rb,
                                                 const float* __restrict__ sq,
                                                 const int* __restrict__ labels,
                                                 unsigned short* __restrict__ K,
                                                 float* __restrict__ out) {
    __shared__ uint8_t apad[80 * 1024];            // occupancy clamp only
    if ((size_t)out == 1) *(volatile uint8_t*)apad = 1;   // keep alive

    const int tid  = threadIdx.x;
    const int wid  = tid >> 6, lane = tid & 63;
    const int q    = lane >> 4, t = lane & 15;
    const int r0   = blockIdx.x * 16;

    // A fragments for the block's 16 rows (held in registers)
    bf16x8 af[4];
    const unsigned short* baseA = Rb + (size_t)(r0 + t) * D + q * 8;
#pragma unroll
    for (int kq = 0; kq < 4; ++kq)
        af[kq] = *(const bf16x8*)(baseA + kq * 32);

    float sqa[4]; int la[4];                       // row scalars (row = q*4+rr)
#pragma unroll
    for (int rr = 0; rr < 4; ++rr) {
        sqa[rr] = sq[r0 + q * 4 + rr];
        la[rr]  = labels[r0 + q * 4 + rr];
    }

    // 256 j-tiles of 16 cols; 8 waves -> 32 tiles/wave; software-pipelined
    const int jt0 = wid * 32;
    int col = jt0 * 16 + t;
    bf16x8 bfr[4];
    {
        const unsigned short* baseB = Rb + (size_t)col * D + q * 8;
#pragma unroll
        for (int kq = 0; kq < 4; ++kq)
            bfr[kq] = *(const bf16x8*)(baseB + kq * 32);
    }
    float sqc = sq[col];
    int   lc  = labels[col];

    for (int i = 0; i < 32; ++i) {
        // prefetch next tile while MFMA+epilogue run on current
        const int jn   = (i < 31) ? (jt0 + i + 1) : (jt0 + 31);
        const int coln = jn * 16 + t;
        bf16x8 bnx[4];
        {
            const unsigned short* baseB = Rb + (size_t)coln * D + q * 8;
#pragma unroll
            for (int kq = 0; kq < 4; ++kq)
                bnx[kq] = *(const bf16x8*)(baseB + kq * 32);
        }
        const float sqn = sq[coln];
        const int   lcn = labels[coln];

        f32x4 acc = (f32x4)0.0f;
#pragma unroll
        for (int kq = 0; kq < 4; ++kq)
            acc = __builtin_amdgcn_mfma_f32_16x16x32_bf16(af[kq], bfr[kq], acc, 0, 0, 0);

#pragma unroll
        for (int rr = 0; rr < 4; ++rr) {           // D: row = q*4+rr, col = t
            float g  = acc[rr];
            float d2 = fmaxf(sqa[rr] + sqc - 2.0f * g, 0.0f);
            float dist = (d2 > 0.0f) ? sqrtf(d2) : 0.0f;
            float s = -dist + ((la[rr] == lc) ? 0.0f : MARGIN_F);
            uint32_t key = xform_key(s);           // sim <= 0.2 -> no ovf on +0x8000
            K[(size_t)(r0 + q * 4 + rr) * B + col] =
                (unsigned short)((key + 0x8000u) >> 16);
        }

#pragma unroll
        for (int kq = 0; kq < 4; ++kq) bfr[kq] = bnx[kq];
        sqc = sqn; lc = lcn; col = coln;
    }
}

// R8 SPLIT, kernel B: rank/loss. ONE WAVE PER ROW. 512 blocks x 512t
// (8 rows/block) -> 2 blocks/CU (LDS-capped: 8KB cand + 56KB pad = 64KB)
// -> 16 waves/CU = 4 waves/SIMD: the stall-cover doubling that the fused
// 148KB-LDS shape could never reach with clean codegen. Everything is
// wave-private -> ZERO __syncthreads. kv = one coalesced 1KB/wave global
// read (L2/L3-hot), pinned in registers; flushes re-scan the register copy.
__global__ __launch_bounds__(512) void rank_loss(const unsigned short* __restrict__ K,
                                                 const int* __restrict__ labels,
                                                 float* __restrict__ out) {
    __shared__ uint32_t cand_c[8][CW];             // 8 KB, wave-private slices
    __shared__ uint8_t  bpad[56 * 1024];           // occupancy clamp only
    if ((size_t)out == 1) *(volatile uint8_t*)bpad = 1;   // keep alive

    const int tid  = threadIdx.x;
    const int wid  = tid >> 6, lane = tid & 63;
    const int row  = blockIdx.x * 8 + wid;
    const int li   = labels[row];
    const int4* lv = (const int4*)labels;

    // zero own slice (wave-private; no barrier needed anywhere in B)
#pragma unroll
    for (int c = 0; c < CW / 64; ++c)
        cand_c[wid][lane + c * 64] = 0u;

    float facc = 0.0f;

    // kv: one coalesced row read, PINNED (asm output can't be rematerialized)
    u32x4 kv[8];
    const unsigned short* krow = K + (size_t)row * B;
#pragma unroll
    for (int qq = 0; qq < 8; ++qq)
        kv[qq] = *(const u32x4*)(krow + (qq * 64 + lane) * 8);
    asm volatile("" : "+v"(kv[0]), "+v"(kv[1]), "+v"(kv[2]), "+v"(kv[3]),
                      "+v"(kv[4]), "+v"(kv[5]), "+v"(kv[6]), "+v"(kv[7]));

    uint64_t mbits = 0;
    uint32_t t1 = 0, t2 = 0;

    // per-qq local top-2 (8 independent chains) + mbits
    {
        uint32_t t1a[8], t2a[8];
#pragma unroll
        for (int qq = 0; qq < 8; ++qq) {
            const int lb = (qq * 64 + lane) * 2;
            int4 la4 = lv[lb], lc4 = lv[lb + 1];
            uint32_t u[8] = {kv[qq].x & 0xFFFFu, kv[qq].x >> 16,
                             kv[qq].y & 0xFFFFu, kv[qq].y >> 16,
                             kv[qq].z & 0xFFFFu, kv[qq].z >> 16,
                             kv[qq].w & 0xFFFFu, kv[qq].w >> 16};
            uint32_t l1 = 0, l2 = 0;
#pragma unroll
            for (int c = 0; c < 8; ++c) {
                uint32_t mn = min(l1, u[c]);
                l1 = max(l1, u[c]);
                l2 = max(l2, mn);
            }
            t1a[qq] = l1; t2a[qq] = l2;
            mbits |= (uint64_t)(la4.x == li) << (qq * 8 + 0);
            mbits |= (uint64_t)(la4.y == li) << (qq * 8 + 1);
            mbits |= (uint64_t)(la4.z == li) << (qq * 8 + 2);
            mbits |= (uint64_t)(la4.w == li) << (qq * 8 + 3);
            mbits |= (uint64_t)(lc4.x == li) << (qq * 8 + 4);
            mbits |= (uint64_t)(lc4.y == li) << (qq * 8 + 5);
            mbits |= (uint64_t)(lc4.z == li) << (qq * 8 + 6);
            mbits |= (uint64_t)(lc4.w == li) << (qq * 8 + 7);
        }
#pragma unroll
        for (int qq = 0; qq < 8; ++qq) {
            uint32_t mn = min(t1, t1a[qq]);
            t1 = max(t1, t1a[qq]);
            t2 = max(t2, mn);
            mn = min(t1, t2a[qq]);
            t1 = max(t1, t2a[qq]);
            t2 = max(t2, mn);
        }
    }

    int kloc = __popcll(mbits);
#pragma unroll
    for (int off = 32; off > 0; off >>= 1) kloc += __shfl_xor(kloc, off);
    const int k = kloc;
    const float kf = (float)k;

    // ballot binary search: T = k-th largest of 128-subset (<= true k-th)
    const int kneed = min(k, 128);
    uint32_t T = 0;
#pragma unroll
    for (int b = 15; b >= 0; --b) {
        uint32_t g = T | (1u << b);
        int c = __popcll(__ballot(t1 >= g)) + __popcll(__ballot(t2 >= g));
        if (c >= kneed) T = g;
    }
    const uint32_t combT = T << 12;

    // gather: winner mask -> wave prefix-sum -> disjoint stores
    int total = 0;
    {
        uint64_t wmask = 0;
#pragma unroll
        for (int qq = 0; qq < 8; ++qq) {
            uint32_t u[8] = {kv[qq].x & 0xFFFFu, kv[qq].x >> 16,
                             kv[qq].y & 0xFFFFu, kv[qq].y >> 16,
                             kv[qq].z & 0xFFFFu, kv[qq].z >> 16,
                             kv[qq].w & 0xFFFFu, kv[qq].w >> 16};
#pragma unroll
            for (int c = 0; c < 8; ++c) {
                int e = qq * 8 + c;
                uint32_t m = (uint32_t)((mbits >> e) & 1);
                wmask |= (uint64_t)((u[c] >= T) | m) << e;
            }
        }
        int cw = __popcll(wmask);
        int inc = cw;
#pragma unroll
        for (int off = 1; off < 64; off <<= 1) {
            int v = __shfl_up(inc, off);
            if (lane >= off) inc += v;
        }
        int mybase = inc - cw;                     // exclusive prefix
        total = __shfl(inc, 63);

#pragma unroll
        for (int qq = 0; qq < 8; ++qq) {
            uint32_t sub = (uint32_t)((wmask >> (qq * 8)) & 0xFFu);
            uint32_t u[8] = {kv[qq].x & 0xFFFFu, kv[qq].x >> 16,
                             kv[qq].y & 0xFFFFu, kv[qq].y >> 16,
                             kv[qq].z & 0xFFFFu, kv[qq].z >> 16,
                             kv[qq].w & 0xFFFFu, kv[qq].w >> 16};
            int jb = (qq * 64 + lane) * 8;
#pragma unroll
            for (int c = 0; c < 8; ++c) {
                if (sub & (1u << c)) {
                    if (mybase < CW) {
                        uint32_t m = (uint32_t)((mbits >> (qq * 8 + c)) & 1);
                        cand_c[wid][mybase] =
                            (u[c] << 12) | (uint32_t)(4095 - (jb + c)) | (m << 31);
                    }
                    ++mybase;
                }
            }
        }
    }
    const int ncand = min(total, CW);

    // own-wave LDS stores must land before own-wave reads
    __builtin_amdgcn_s_waitcnt(0);

    // ---- owned candidates -> registers (slots lane, lane+64, +128, +192)
    uint32_t cr0 = cand_c[wid][lane];
    uint32_t cr1 = cand_c[wid][lane + 64];
    uint32_t cr2 = cand_c[wid][lane + 128];
    uint32_t cr3 = cand_c[wid][lane + 192];
    uint32_t mycomb[4] = {cr0 & 0x7FFFFFFFu, cr1 & 0x7FFFFFFFu,
                          cr2 & 0x7FFFFFFFu, cr3 & 0x7FFFFFFFu};
    int mym[4]  = {(int)(cr0 >> 31), (int)(cr1 >> 31),
                   (int)(cr2 >> 31), (int)(cr3 >> 31)};
    int myok[4] = {lane < ncand, lane + 64 < ncand,
                   lane + 128 < ncand, lane + 192 < ncand};
    int myc[4]  = {0, 0, 0, 0};

    // ---- exact-rank: chunked broadcast scan (8 cands / 2 b128 per chunk)
    const int npad = (ncand + 7) & ~7;
    for (int c0i = 0; c0i < npad; c0i += 8) {
        u32x4 a = *(const u32x4*)&cand_c[wid][c0i];
        u32x4 b = *(const u32x4*)&cand_c[wid][c0i + 4];
        uint32_t vv[8] = {a.x, a.y, a.z, a.w, b.x, b.y, b.z, b.w};
#pragma unroll
        for (int e = 0; e < 8; ++e) {
            uint32_t vm = vv[e] & 0x7FFFFFFFu;
#pragma unroll
            for (int j = 0; j < 4; ++j)
                myc[j] += (vm > mycomb[j]) ? 1 : 0;
        }
    }

    // apply above-T terms per owned candidate (each owned by one lane)
#pragma unroll
    for (int j = 0; j < 4; ++j) {
        if (myok[j] && mycomb[j] >= combT) {
            int rank = 1 + myc[j];
            float v = unxform16(mycomb[j] >> 12);
            if (!mym[j] && rank <= k)
                facc += v * (0.5f + ((kf - (float)rank + 1.0f) / kf) * 0.5f);
            else if (mym[j] && rank > k)
                facc -= v * (0.5f + (((float)rank - kf) / (float)(B - k)) * 0.5f);
        }
    }

    // ---- below-T matches (rank > k guaranteed): detect from registers,
    // extract via ballot, flush up to 4 pivots per kv re-scan (kv pinned)
    uint32_t p0 = 0xFFFFFFFFu, p1 = 0xFFFFFFFFu, p2 = 0xFFFFFFFFu, p3 = 0xFFFFFFFFu;

    auto flush4 = [&](int npv) {
        int c0 = 0, c1 = 0, c2 = 0, c3 = 0;
#pragma unroll
        for (int qq = 0; qq < 8; ++qq) {
            uint32_t u[8] = {kv[qq].x & 0xFFFFu, kv[qq].x >> 16,
                             kv[qq].y & 0xFFFFu, kv[qq].y >> 16,
                             kv[qq].z & 0xFFFFu, kv[qq].z >> 16,
                             kv[qq].w & 0xFFFFu, kv[qq].w >> 16};
            int jb = (qq * 64 + lane) * 8;
#pragma unroll
            for (int cc = 0; cc < 8; ++cc) {
                uint32_t ce = (u[cc] << 12) | (uint32_t)(4095 - (jb + cc));
                c0 += (ce > p0) ? 1 : 0;  c1 += (ce > p1) ? 1 : 0;
                c2 += (ce > p2) ? 1 : 0;  c3 += (ce > p3) ? 1 : 0;
            }
        }
#pragma unroll
        for (int off = 32; off > 0; off >>= 1) {
            c0 += __shfl_xor(c0, off); c1 += __shfl_xor(c1, off);
            c2 += __shfl_xor(c2, off); c3 += __shfl_xor(c3, off);
        }
        if (lane == 0) {
            if (npv > 0) facc -= unxform16(p0 >> 12) * (0.5f + (((float)(1 + c0) - kf) / (float)(B - k)) * 0.5f);
            if (npv > 1) facc -= unxform16(p1 >> 12) * (0.5f + (((float)(1 + c1) - kf) / (float)(B - k)) * 0.5f);
            if (npv > 2) facc -= unxform16(p2 >> 12) * (0.5f + (((float)(1 + c2) - kf) / (float)(B - k)) * 0.5f);
            if (npv > 3) facc -= unxform16(p3 >> 12) * (0.5f + (((float)(1 + c3) - kf) / (float)(B - k)) * 0.5f);
        }
        p0 = p1 = p2 = p3 = 0xFFFFFFFFu;
    };

    int np = 0;
#pragma unroll
    for (int j = 0; j < 4; ++j) {
        uint64_t mg = __ballot(myok[j] && mym[j] && (mycomb[j] < combT));
        while (mg) {
            int src = __ffsll((unsigned long long)mg) - 1;
            mg &= mg - 1;
            uint32_t pc;
            if (j == 0)      pc = __shfl(mycomb[0], src);
            else if (j == 1) pc = __shfl(mycomb[1], src);
            else if (j == 2) pc = __shfl(mycomb[2], src);
            else             pc = __shfl(mycomb[3], src);
            switch (np) {
                case 0: p0 = pc; break; case 1: p1 = pc; break;
                case 2: p2 = pc; break; default: p3 = pc; break;
            }
            ++np;
            if (np == 4) { flush4(4); np = 0; }
        }
    }
    if (np > 0) flush4(np);

#pragma unroll
    for (int off = 32; off > 0; off >>= 1) facc += __shfl_xor(facc, off);
    if (lane == 0) atomicAdd(out, facc);
}

extern "C" void kernel_launch(void* const* d_in, const int* in_sizes, int n_in,
                              void* d_out, int out_size, void* d_ws, size_t ws_size,
                              hipStream_t stream) {
    const float* R      = (const float*)d_in[0];
    const int*   labels = (const int*)d_in[1];
    float* out = (float*)d_out;

    float*          sq = (float*)d_ws;                               // 16 KB
    unsigned short* Rb = (unsigned short*)((char*)d_ws + 16 * 1024); // 1 MB
    unsigned short* K  = (unsigned short*)((char*)d_ws + 16 * 1024
                                           + (size_t)B * D * 2);     // 32 MB keys

    hipLaunchKernelGGL(prep_kernel, dim3(B / 4), dim3(256), 0, stream, R, sq, Rb, out);
    hipLaunchKernelGGL(gram_keys, dim3(B / 16), dim3(512), 0, stream,
                       Rb, sq, labels, K, out);
    hipLaunchKernelGGL(rank_loss, dim3(B / 8), dim3(512), 0, stream,
                       K, labels, out);
}

// Round 10
// 132.719 us; speedup vs baseline: 1.3033x; 1.3033x over previous
//
#include <hip/hip_runtime.h>
#include <cstdint>
#include <cstddef>

#define B 4096
#define D 128
#define MARGIN_F 0.2f
#define CW 256            // per-row candidate capacity
#define ROWS 16           // rows per block
#define SSTR 4104         // key-strip stride (ushorts): rows 16B-aligned, bank-skewed

typedef short bf16x8 __attribute__((ext_vector_type(8)));
typedef float f32x4 __attribute__((ext_vector_type(4)));
typedef uint32_t u32x4 __attribute__((ext_vector_type(4)));

// order-preserving float->uint (ascending uint == ascending float)
__device__ __forceinline__ uint32_t xform_key(float f) {
    uint32_t u = __float_as_uint(f);
    return u ^ (uint32_t)((((int32_t)u) >> 31) | 0x80000000);
}
// decode 16-bit truncated key (bucket center under round-to-nearest encode)
__device__ __forceinline__ float unxform16(uint32_t k16) {
    uint32_t u = k16 << 16;
    u = (u & 0x80000000u) ? (u ^ 0x80000000u) : ~u;
    return __uint_as_float(u);
}
__device__ __forceinline__ unsigned short f2bf(float f) {   // round-nearest-even
    uint32_t u = __float_as_uint(f);
    return (unsigned short)((u + 0x7FFFu + ((u >> 16) & 1u)) >> 16);
}

// fused: zero out, sq[i] = ||R[i]||^2, R -> Rb (bf16 rne)
__global__ __launch_bounds__(256) void prep_kernel(const float* __restrict__ R,
                                                   float* __restrict__ sq,
                                                   unsigned short* __restrict__ Rb,
                                                   float* __restrict__ out) {
    if (blockIdx.x == 0 && threadIdx.x == 0) out[0] = 0.0f;
    int wave = threadIdx.x >> 6;
    int lane = threadIdx.x & 63;
    int row  = blockIdx.x * 4 + wave;
    const float2* R2 = (const float2*)R + (size_t)row * (D / 2);
    float2 v = R2[lane];
    ushort2 o; o.x = f2bf(v.x); o.y = f2bf(v.y);
    *(ushort2*)(Rb + (size_t)row * D + lane * 2) = o;
    float s = v.x * v.x + v.y * v.y;
#pragma unroll
    for (int off = 32; off > 0; off >>= 1) s += __shfl_down(s, off);
    if (lane == 0) sq[row] = s;
}

// FUSED, R9 (resubmit; round-9 bench was an infra failure, not a verdict):
// 16 rows/block, 512 threads. 148KB LDS hard-pins 1 block/CU (8 waves) ->
// the allocator has NO reachable occupancy step -> grants registers freely
// (the R4/R5-proven clean regime; R1/2/6/7 crunches all came from reachable
// steps). R8 lesson: TLP never engages on this kernel. New lever: ILP --
// each wave processes its TWO rows INTERLEAVED, so every serial stall
// (kv loads, top-2 chains, 16-iter binary search, prefix sums, rank-scan
// LDS broadcasts) has an independent twin chain covering it within the
// wave. Phase 1 gets next-tile prefetch (B/sq/label) for the same reason.
__global__ __launch_bounds__(512) void fused_loss(const unsigned short* __restrict__ Rb,
                                                  const float* __restrict__ sq,
                                                  const int* __restrict__ labels,
                                                  float* __restrict__ out) {
    __shared__ unsigned short S[ROWS * SSTR];      // 131,328 B key strip
    __shared__ uint32_t cand_c[ROWS][CW];          // 16 KB: comb | (match<<31)

    const int tid  = threadIdx.x;
    const int wid  = tid >> 6, lane = tid & 63;
    const int q    = lane >> 4, t = lane & 15;
    const int r0   = blockIdx.x * ROWS;

    // zero cand_c (pad-safety for the chunked rank scan)
    {
        uint32_t* cz = &cand_c[0][0];
#pragma unroll
        for (int c = 0; c < (ROWS * CW) / 512; ++c)
            cz[tid + c * 512] = 0u;
    }

    // ---- phase 1: A fragments for the block's 16 rows (held in registers)
    bf16x8 af[4];
    const unsigned short* baseA = Rb + (size_t)(r0 + t) * D + q * 8;
#pragma unroll
    for (int kq = 0; kq < 4; ++kq)
        af[kq] = *(const bf16x8*)(baseA + kq * 32);

    float sqa[4]; int la[4];                       // epilogue row scalars (row = q*4+rr)
#pragma unroll
    for (int rr = 0; rr < 4; ++rr) {
        sqa[rr] = sq[r0 + q * 4 + rr];
        la[rr]  = labels[r0 + q * 4 + rr];
    }

    // 256 j-tiles of 16 cols; 8 waves -> 32 tiles/wave; software-pipelined
    {
        const int jt0 = wid * 32;
        int col = jt0 * 16 + t;
        bf16x8 bfr[4];
        {
            const unsigned short* baseB = Rb + (size_t)col * D + q * 8;
#pragma unroll
            for (int kq = 0; kq < 4; ++kq)
                bfr[kq] = *(const bf16x8*)(baseB + kq * 32);
        }
        float sqc = sq[col];
        int   lc  = labels[col];

        for (int i = 0; i < 32; ++i) {
            const int jn   = (i < 31) ? (jt0 + i + 1) : (jt0 + 31);
            const int coln = jn * 16 + t;
            bf16x8 bnx[4];
            {
                const unsigned short* baseB = Rb + (size_t)coln * D + q * 8;
#pragma unroll
                for (int kq = 0; kq < 4; ++kq)
                    bnx[kq] = *(const bf16x8*)(baseB + kq * 32);
            }
            const float sqn = sq[coln];
            const int   lcn = labels[coln];

            f32x4 acc = (f32x4)0.0f;
#pragma unroll
            for (int kq = 0; kq < 4; ++kq)
                acc = __builtin_amdgcn_mfma_f32_16x16x32_bf16(af[kq], bfr[kq], acc, 0, 0, 0);

#pragma unroll
            for (int rr = 0; rr < 4; ++rr) {       // D: row = q*4+rr, col = t
                float g  = acc[rr];
                float d2 = fmaxf(sqa[rr] + sqc - 2.0f * g, 0.0f);
                float dist = (d2 > 0.0f) ? sqrtf(d2) : 0.0f;
                float s = -dist + ((la[rr] == lc) ? 0.0f : MARGIN_F);
                uint32_t key = xform_key(s);       // sim <= 0.2 -> no ovf on +0x8000
                S[(q * 4 + rr) * SSTR + col] = (unsigned short)((key + 0x8000u) >> 16);
            }

#pragma unroll
            for (int kq = 0; kq < 4; ++kq) bfr[kq] = bnx[kq];
            sqc = sqn; lc = lcn; col = coln;
        }
    }
    __syncthreads();                               // strip + zeroed cand_c visible

    // ---- phase 2: each wave owns rows rA=wid*2, rB=wid*2+1, INTERLEAVED
    float facc = 0.0f;
    const int4* lv = (const int4*)labels;

    const int rA = wid * 2, rB = wid * 2 + 1;
    const int liA = labels[r0 + rA];
    const int liB = labels[r0 + rB];

    // kv for both rows: 16 independent b128 LDS reads
    u32x4 kvA[8], kvB[8];
#pragma unroll
    for (int qq = 0; qq < 8; ++qq) {
        kvA[qq] = *(u32x4*)(&S[rA * SSTR + (qq * 64 + lane) * 8]);
        kvB[qq] = *(u32x4*)(&S[rB * SSTR + (qq * 64 + lane) * 8]);
    }

    uint64_t mbA = 0, mbB = 0;
    uint32_t t1A = 0, t2A = 0, t1B = 0, t2B = 0;

    // top-2 + mbits for both rows, label loads shared
#pragma unroll
    for (int qq = 0; qq < 8; ++qq) {
        const int lb = (qq * 64 + lane) * 2;
        int4 la4 = lv[lb], lc4 = lv[lb + 1];
        uint32_t uA[8] = {kvA[qq].x & 0xFFFFu, kvA[qq].x >> 16,
                          kvA[qq].y & 0xFFFFu, kvA[qq].y >> 16,
                          kvA[qq].z & 0xFFFFu, kvA[qq].z >> 16,
                          kvA[qq].w & 0xFFFFu, kvA[qq].w >> 16};
        uint32_t uB[8] = {kvB[qq].x & 0xFFFFu, kvB[qq].x >> 16,
                          kvB[qq].y & 0xFFFFu, kvB[qq].y >> 16,
                          kvB[qq].z & 0xFFFFu, kvB[qq].z >> 16,
                          kvB[qq].w & 0xFFFFu, kvB[qq].w >> 16};
#pragma unroll
        for (int c = 0; c < 8; ++c) {              // two independent chains
            uint32_t mnA = min(t1A, uA[c]);
            t1A = max(t1A, uA[c]);
            t2A = max(t2A, mnA);
            uint32_t mnB = min(t1B, uB[c]);
            t1B = max(t1B, uB[c]);
            t2B = max(t2B, mnB);
        }
        mbA |= (uint64_t)(la4.x == liA) << (qq * 8 + 0);
        mbA |= (uint64_t)(la4.y == liA) << (qq * 8 + 1);
        mbA |= (uint64_t)(la4.z == liA) << (qq * 8 + 2);
        mbA |= (uint64_t)(la4.w == liA) << (qq * 8 + 3);
        mbA |= (uint64_t)(lc4.x == liA) << (qq * 8 + 4);
        mbA |= (uint64_t)(lc4.y == liA) << (qq * 8 + 5);
        mbA |= (uint64_t)(lc4.z == liA) << (qq * 8 + 6);
        mbA |= (uint64_t)(lc4.w == liA) << (qq * 8 + 7);
        mbB |= (uint64_t)(la4.x == liB) << (qq * 8 + 0);
        mbB |= (uint64_t)(la4.y == liB) << (qq * 8 + 1);
        mbB |= (uint64_t)(la4.z == liB) << (qq * 8 + 2);
        mbB |= (uint64_t)(la4.w == liB) << (qq * 8 + 3);
        mbB |= (uint64_t)(lc4.x == liB) << (qq * 8 + 4);
        mbB |= (uint64_t)(lc4.y == liB) << (qq * 8 + 5);
        mbB |= (uint64_t)(lc4.z == liB) << (qq * 8 + 6);
        mbB |= (uint64_t)(lc4.w == liB) << (qq * 8 + 7);
    }

    // k-reduce: two interleaved shfl chains
    int klA = __popcll(mbA), klB = __popcll(mbB);
#pragma unroll
    for (int off = 32; off > 0; off >>= 1) {
        klA += __shfl_xor(klA, off);
        klB += __shfl_xor(klB, off);
    }
    const int kA = klA, kB = klB;
    const float kfA = (float)kA, kfB = (float)kB;

    // ballot binary search: both rows per iteration (independent)
    const int kneedA = min(kA, 128), kneedB = min(kB, 128);
    uint32_t TA = 0, TB = 0;
#pragma unroll
    for (int b = 15; b >= 0; --b) {
        uint32_t gA = TA | (1u << b), gB = TB | (1u << b);
        int cA = __popcll(__ballot(t1A >= gA)) + __popcll(__ballot(t2A >= gA));
        int cB = __popcll(__ballot(t1B >= gB)) + __popcll(__ballot(t2B >= gB));
        if (cA >= kneedA) TA = gA;
        if (cB >= kneedB) TB = gB;
    }
    const uint32_t combTA = TA << 12, combTB = TB << 12;

    // gather both rows: winner masks -> interleaved prefix sums -> stores
    uint64_t wmA = 0, wmB = 0;
#pragma unroll
    for (int qq = 0; qq < 8; ++qq) {
        uint32_t uA[8] = {kvA[qq].x & 0xFFFFu, kvA[qq].x >> 16,
                          kvA[qq].y & 0xFFFFu, kvA[qq].y >> 16,
                          kvA[qq].z & 0xFFFFu, kvA[qq].z >> 16,
                          kvA[qq].w & 0xFFFFu, kvA[qq].w >> 16};
        uint32_t uB[8] = {kvB[qq].x & 0xFFFFu, kvB[qq].x >> 16,
                          kvB[qq].y & 0xFFFFu, kvB[qq].y >> 16,
                          kvB[qq].z & 0xFFFFu, kvB[qq].z >> 16,
                          kvB[qq].w & 0xFFFFu, kvB[qq].w >> 16};
#pragma unroll
        for (int c = 0; c < 8; ++c) {
            int e = qq * 8 + c;
            uint32_t mA = (uint32_t)((mbA >> e) & 1);
            uint32_t mB = (uint32_t)((mbB >> e) & 1);
            wmA |= (uint64_t)((uA[c] >= TA) | mA) << e;
            wmB |= (uint64_t)((uB[c] >= TB) | mB) << e;
        }
    }
    int cwA = __popcll(wmA), cwB = __popcll(wmB);
    int incA = cwA, incB = cwB;
#pragma unroll
    for (int off = 1; off < 64; off <<= 1) {
        int vA = __shfl_up(incA, off);
        int vB = __shfl_up(incB, off);
        if (lane >= off) { incA += vA; incB += vB; }
    }
    int baseAi = incA - cwA, baseBi = incB - cwB;  // exclusive prefixes
    const int totalA = __shfl(incA, 63), totalB = __shfl(incB, 63);

#pragma unroll
    for (int qq = 0; qq < 8; ++qq) {
        uint32_t subA = (uint32_t)((wmA >> (qq * 8)) & 0xFFu);
        uint32_t subB = (uint32_t)((wmB >> (qq * 8)) & 0xFFu);
        uint32_t uA[8] = {kvA[qq].x & 0xFFFFu, kvA[qq].x >> 16,
                          kvA[qq].y & 0xFFFFu, kvA[qq].y >> 16,
                          kvA[qq].z & 0xFFFFu, kvA[qq].z >> 16,
                          kvA[qq].w & 0xFFFFu, kvA[qq].w >> 16};
        uint32_t uB[8] = {kvB[qq].x & 0xFFFFu, kvB[qq].x >> 16,
                          kvB[qq].y & 0xFFFFu, kvB[qq].y >> 16,
                          kvB[qq].z & 0xFFFFu, kvB[qq].z >> 16,
                          kvB[qq].w & 0xFFFFu, kvB[qq].w >> 16};
        int jb = (qq * 64 + lane) * 8;
#pragma unroll
        for (int c = 0; c < 8; ++c) {
            if (subA & (1u << c)) {
                if (baseAi < CW) {
                    uint32_t m = (uint32_t)((mbA >> (qq * 8 + c)) & 1);
                    cand_c[rA][baseAi] = (uA[c] << 12) | (uint32_t)(4095 - (jb + c)) | (m << 31);
                }
                ++baseAi;
            }
            if (subB & (1u << c)) {
                if (baseBi < CW) {
                    uint32_t m = (uint32_t)((mbB >> (qq * 8 + c)) & 1);
                    cand_c[rB][baseBi] = (uB[c] << 12) | (uint32_t)(4095 - (jb + c)) | (m << 31);
                }
                ++baseBi;
            }
        }
    }
    const int ncandA = min(totalA, CW), ncandB = min(totalB, CW);

    // own-wave LDS stores must land before own-wave reads
    __builtin_amdgcn_s_waitcnt(0);

    // ---- owned candidates -> registers, both rows (8 independent LDS reads)
    uint32_t crA0 = cand_c[rA][lane],        crB0 = cand_c[rB][lane];
    uint32_t crA1 = cand_c[rA][lane + 64],   crB1 = cand_c[rB][lane + 64];
    uint32_t crA2 = cand_c[rA][lane + 128],  crB2 = cand_c[rB][lane + 128];
    uint32_t crA3 = cand_c[rA][lane + 192],  crB3 = cand_c[rB][lane + 192];
    uint32_t mcA[4] = {crA0 & 0x7FFFFFFFu, crA1 & 0x7FFFFFFFu,
                       crA2 & 0x7FFFFFFFu, crA3 & 0x7FFFFFFFu};
    uint32_t mcB[4] = {crB0 & 0x7FFFFFFFu, crB1 & 0x7FFFFFFFu,
                       crB2 & 0x7FFFFFFFu, crB3 & 0x7FFFFFFFu};
    int mmA[4] = {(int)(crA0 >> 31), (int)(crA1 >> 31), (int)(crA2 >> 31), (int)(crA3 >> 31)};
    int mmB[4] = {(int)(crB0 >> 31), (int)(crB1 >> 31), (int)(crB2 >> 31), (int)(crB3 >> 31)};
    int okA[4] = {lane < ncandA, lane + 64 < ncandA, lane + 128 < ncandA, lane + 192 < ncandA};
    int okB[4] = {lane < ncandB, lane + 64 < ncandB, lane + 128 < ncandB, lane + 192 < ncandB};
    int cntA[4] = {0, 0, 0, 0}, cntB[4] = {0, 0, 0, 0};

    // ---- exact-rank: combined chunked broadcast scan over both cand lists
    const int npadA = (ncandA + 7) & ~7;
    const int npadB = (ncandB + 7) & ~7;
    const int npadM = npadA > npadB ? npadA : npadB;
    for (int c0i = 0; c0i < npadM; c0i += 8) {
        if (c0i < npadA) {
            u32x4 a = *(const u32x4*)&cand_c[rA][c0i];
            u32x4 b = *(const u32x4*)&cand_c[rA][c0i + 4];
            uint32_t vv[8] = {a.x, a.y, a.z, a.w, b.x, b.y, b.z, b.w};
#pragma unroll
            for (int e = 0; e < 8; ++e) {
                uint32_t vm = vv[e] & 0x7FFFFFFFu;
#pragma unroll
                for (int j = 0; j < 4; ++j)
                    cntA[j] += (vm > mcA[j]) ? 1 : 0;
            }
        }
        if (c0i < npadB) {
            u32x4 a = *(const u32x4*)&cand_c[rB][c0i];
            u32x4 b = *(const u32x4*)&cand_c[rB][c0i + 4];
            uint32_t vv[8] = {a.x, a.y, a.z, a.w, b.x, b.y, b.z, b.w};
#pragma unroll
            for (int e = 0; e < 8; ++e) {
                uint32_t vm = vv[e] & 0x7FFFFFFFu;
#pragma unroll
                for (int j = 0; j < 4; ++j)
                    cntB[j] += (vm > mcB[j]) ? 1 : 0;
            }
        }
    }

    // apply above-T terms, row A then row B
#pragma unroll
    for (int j = 0; j < 4; ++j) {
        if (okA[j] && mcA[j] >= combTA) {
            int rank = 1 + cntA[j];
            float v = unxform16(mcA[j] >> 12);
            if (!mmA[j] && rank <= kA)
                facc += v * (0.5f + ((kfA - (float)rank + 1.0f) / kfA) * 0.5f);
            else if (mmA[j] && rank > kA)
                facc -= v * (0.5f + (((float)rank - kfA) / (float)(B - kA)) * 0.5f);
        }
        if (okB[j] && mcB[j] >= combTB) {
            int rank = 1 + cntB[j];
            float v = unxform16(mcB[j] >> 12);
            if (!mmB[j] && rank <= kB)
                facc += v * (0.5f + ((kfB - (float)rank + 1.0f) / kfB) * 0.5f);
            else if (mmB[j] && rank > kB)
                facc -= v * (0.5f + (((float)rank - kfB) / (float)(B - kB)) * 0.5f);
        }
    }

    // ---- below-T matches (rank > k guaranteed): register detection,
    // ballot extraction, flush4 re-scans the register kv copy. Generic
    // over the row's register set (specializes at each call site).
    auto below_t = [&](auto& kvr, const uint32_t* mcr, const int* mmr, const int* okr,
                       uint32_t combTr, float kfr, int kr) {
        uint32_t p0 = 0xFFFFFFFFu, p1 = 0xFFFFFFFFu, p2 = 0xFFFFFFFFu, p3 = 0xFFFFFFFFu;

        auto flush4 = [&](int npv) {
            int c0 = 0, c1 = 0, c2 = 0, c3 = 0;
#pragma unroll
            for (int qq = 0; qq < 8; ++qq) {
                uint32_t u[8] = {kvr[qq].x & 0xFFFFu, kvr[qq].x >> 16,
                                 kvr[qq].y & 0xFFFFu, kvr[qq].y >> 16,
                                 kvr[qq].z & 0xFFFFu, kvr[qq].z >> 16,
                                 kvr[qq].w & 0xFFFFu, kvr[qq].w >> 16};
                int jb = (qq * 64 + lane) * 8;
#pragma unroll
                for (int cc = 0; cc < 8; ++cc) {
                    uint32_t ce = (u[cc] << 12) | (uint32_t)(4095 - (jb + cc));
                    c0 += (ce > p0) ? 1 : 0;  c1 += (ce > p1) ? 1 : 0;
                    c2 += (ce > p2) ? 1 : 0;  c3 += (ce > p3) ? 1 : 0;
                }
            }
#pragma unroll
            for (int off = 32; off > 0; off >>= 1) {
                c0 += __shfl_xor(c0, off); c1 += __shfl_xor(c1, off);
                c2 += __shfl_xor(c2, off); c3 += __shfl_xor(c3, off);
            }
            if (lane == 0) {
                if (npv > 0) facc -= unxform16(p0 >> 12) * (0.5f + (((float)(1 + c0) - kfr) / (float)(B - kr)) * 0.5f);
                if (npv > 1) facc -= unxform16(p1 >> 12) * (0.5f + (((float)(1 + c1) - kfr) / (float)(B - kr)) * 0.5f);
                if (npv > 2) facc -= unxform16(p2 >> 12) * (0.5f + (((float)(1 + c2) - kfr) / (float)(B - kr)) * 0.5f);
                if (npv > 3) facc -= unxform16(p3 >> 12) * (0.5f + (((float)(1 + c3) - kfr) / (float)(B - kr)) * 0.5f);
            }
            p0 = p1 = p2 = p3 = 0xFFFFFFFFu;
        };

        int np = 0;
#pragma unroll
        for (int j = 0; j < 4; ++j) {
            uint64_t mg = __ballot(okr[j] && mmr[j] && (mcr[j] < combTr));
            while (mg) {
                int src = __ffsll((unsigned long long)mg) - 1;
                mg &= mg - 1;
                uint32_t pc;
                if (j == 0)      pc = __shfl(mcr[0], src);
                else if (j == 1) pc = __shfl(mcr[1], src);
                else if (j == 2) pc = __shfl(mcr[2], src);
                else             pc = __shfl(mcr[3], src);
                switch (np) {
                    case 0: p0 = pc; break; case 1: p1 = pc; break;
                    case 2: p2 = pc; break; default: p3 = pc; break;
                }
                ++np;
                if (np == 4) { flush4(4); np = 0; }
            }
        }
        if (np > 0) flush4(np);
    };

    below_t(kvA, mcA, mmA, okA, combTA, kfA, kA);
    below_t(kvB, mcB, mmB, okB, combTB, kfB, kB);

#pragma unroll
    for (int off = 32; off > 0; off >>= 1) facc += __shfl_xor(facc, off);
    if (lane == 0) atomicAdd(out, facc);
}

extern "C" void kernel_launch(void* const* d_in, const int* in_sizes, int n_in,
                              void* d_out, int out_size, void* d_ws, size_t ws_size,
                              hipStream_t stream) {
    const float* R      = (const float*)d_in[0];
    const int*   labels = (const int*)d_in[1];
    float* out = (float*)d_out;

    float*          sq = (float*)d_ws;                               // 16 KB
    unsigned short* Rb = (unsigned short*)((char*)d_ws + 16 * 1024); // 1 MB

    hipLaunchKernelGGL(prep_kernel, dim3(B / 4), dim3(256), 0, stream, R, sq, Rb, out);
    hipLaunchKernelGGL(fused_loss, dim3(B / ROWS), dim3(512), 0, stream,
                       Rb, sq, labels, out);
}